// Round 7
// baseline (441.851 us; speedup 1.0000x reference)
//
#include <hip/hip_runtime.h>

#define D_NODE 128
#define D_EDGE 64
#define D_IN   192
#define NEG    0.01f
#define LN_EPS 1e-5f

typedef short bf16x8 __attribute__((ext_vector_type(8)));
typedef float f32x4  __attribute__((ext_vector_type(4)));

__device__ __forceinline__ unsigned f2bf(float f) {
    unsigned u = __builtin_bit_cast(unsigned, f);
    return (u + 0x7FFFu + ((u >> 16) & 1u)) >> 16;   // RNE
}
__device__ __forceinline__ unsigned pk2(float a, float b) {
    return f2bf(a) | (f2bf(b) << 16);
}
// HW packed f32->bf16 (RNE), 1 instr for 2 values (no builtin on gfx950)
__device__ __forceinline__ unsigned cvtpk(float a, float b) {
    unsigned r;
    asm("v_cvt_pk_bf16_f32 %0, %1, %2" : "=v"(r) : "v"(a), "v"(b));
    return r;
}
// 16-lane sum via DPP (pure VALU, no LDS routing)
template <int C>
__device__ __forceinline__ float dppadd(float v) {
    int y = __builtin_amdgcn_update_dpp(0, __builtin_bit_cast(int, v),
                                        C, 0xF, 0xF, true);
    return v + __builtin_bit_cast(float, y);
}
__device__ __forceinline__ float red16(float v) {
    v = dppadd<0xB1>(v);
    v = dppadd<0x4E>(v);
    v = dppadd<0x141>(v);
    v = dppadd<0x140>(v);
    return v;
}

// ---------------------------------------------------------------------------
// Merged first stage: pack x -> bf16 AND histogram edge destinations.
// (Both only depend on inputs; one launch instead of two.)
// ---------------------------------------------------------------------------
__global__ void k_pre(const float* __restrict__ x, unsigned short* __restrict__ xb,
                      int n8, const int* __restrict__ ei, int* __restrict__ hist,
                      int E) {
    int i = blockIdx.x * blockDim.x + threadIdx.x;
    int stride = gridDim.x * blockDim.x;
    for (int t = i; t < n8; t += stride) {
        const float4* p = (const float4*)x + (size_t)t * 2;
        float4 a = p[0], b = p[1];
        uint4 o;
        o.x = pk2(a.x, a.y); o.y = pk2(a.z, a.w);
        o.z = pk2(b.x, b.y); o.w = pk2(b.z, b.w);
        ((uint4*)xb)[t] = o;
    }
    for (int e = i; e < E; e += stride) atomicAdd(&hist[ei[E + e]], 1);
}

__global__ __launch_bounds__(1024) void k_scanA(const int* __restrict__ hist,
                                                int* __restrict__ base,
                                                int* __restrict__ blockTot, int N) {
    __shared__ int wsum[16], woff[16];
    const int t = threadIdx.x, b = blockIdx.x;
    const int i = b * 1024 + t;
    const int lane = t & 63, w = t >> 6;
    int v = (i < N) ? hist[i] : 0;
    int x = v;
    #pragma unroll
    for (int d = 1; d < 64; d <<= 1) { int u = __shfl_up(x, d); if (lane >= d) x += u; }
    if (lane == 63) wsum[w] = x;
    __syncthreads();
    if (t < 16) {
        int y = wsum[t];
        #pragma unroll
        for (int d = 1; d < 16; d <<= 1) { int u = __shfl_up(y, d, 16); if (t >= d) y += u; }
        woff[t] = y - wsum[t];
    }
    __syncthreads();
    int incl = x + woff[w];
    if (i < N) base[i] = incl - v;            // exclusive within block
    if (t == 1023) blockTot[b] = incl;
}

// scanC with scanB folded in: every block's first wave redundantly scans the
// <=64 block totals (read-only blockTot) and picks its own exclusive offset.
__global__ __launch_bounds__(1024) void k_scanC(int* __restrict__ base,
                                                const int* __restrict__ blockTot,
                                                int N, int NB) {
    __shared__ int off_sh;
    const int t = threadIdx.x;
    if (t < 64) {
        int v = (t < NB) ? blockTot[t] : 0;
        int x = v;
        #pragma unroll
        for (int d = 1; d < 64; d <<= 1) { int u = __shfl_up(x, d); if (t >= d) x += u; }
        if (t == blockIdx.x) off_sh = x - v;  // exclusive offset for this block
    }
    __syncthreads();
    int i = blockIdx.x * 1024 + t;
    if (i < N) base[i] += off_sh;
}

// meta[p] = (srcrow, dstcol, eid, 0): ONE 16B scattered store per edge.
__global__ void k_bucket(const int* __restrict__ ei, int* __restrict__ base,
                         int4* __restrict__ meta, int E) {
    int i = blockIdx.x * blockDim.x + threadIdx.x;
    int stride = gridDim.x * blockDim.x;
    for (int e = i; e < E; e += stride) {
        int c = ei[E + e];
        int r = ei[e];
        int p = atomicAdd(&base[c], 1);       // consumes base (cursor)
        meta[p] = make_int4(r, c, e, 0);
    }
}

// ---------------------------------------------------------------------------
// Edge kernel (UNCHANGED from round 6 — 146us, protect it):
// 2-barrier pipeline + register prefetch; post-B2 wave-local seg-reduce via
// MFMA with in-register P^T; DPP LN reduce; cvt_pk packing; int4 meta.
// ---------------------------------------------------------------------------
__global__ __launch_bounds__(256) void edge_mfma_seg(
    const unsigned short* __restrict__ xb,
    const float* __restrict__ edge_attr,
    const int4*  __restrict__ meta,
    const float* __restrict__ W1,
    const float* __restrict__ b1,
    const float* __restrict__ g1,
    const float* __restrict__ be1,
    float* __restrict__ sums,
    int E, int ntiles)
{
    __shared__ __align__(16) unsigned short h[64][200];   // 25.6 KB
    __shared__ float rS [64][4], rS2[64][4];
    __shared__ int   scol2[2][64];
    __shared__ int   rdest[64];

    const int tid = threadIdx.x;
    const int w   = tid >> 6;
    const int l   = tid & 63;
    const int lm  = l & 15;
    const int q   = l >> 4;
    const int q8  = q * 8;
    const int e   = tid >> 2;                 // = 16w + (l>>2): wave-aligned rows
    const int qq  = tid & 3;

    unsigned short (*yT)[64] = (unsigned short (*)[64])(&h[w * 16][0]);

    bf16x8 Bfr[2][6];
    float  b1v[2], g1v[2], bev[2];
    #pragma unroll
    for (int c2 = 0; c2 < 2; ++c2) {
        const int n = (2 * w + c2) * 16 + lm;
        b1v[c2] = b1[n]; g1v[c2] = g1[n]; bev[c2] = be1[n];
        #pragma unroll
        for (int kt = 0; kt < 6; ++kt) {
            bf16x8 f;
            #pragma unroll
            for (int j = 0; j < 8; ++j)
                f[j] = (short)f2bf(W1[(kt * 32 + q8 + j) * 128 + n]);
            Bfr[c2][kt] = f;
        }
    }

    const int stride_t = gridDim.x;
    int tile = blockIdx.x;
    int pp   = 0;

    uint4  xr0, xr1, xr2, xr3;
    float4 af0, af1, af2, af3;
    int    sc;
    bool   vld;
    {
        const int ge = tile * 64 + e;
        vld = (ge < E);
        if (vld) {
            const int4 mt = meta[ge];
            const uint4* xr = (const uint4*)(xb + (size_t)mt.x * D_NODE) + qq * 4;
            xr0 = xr[0]; xr1 = xr[1]; xr2 = xr[2]; xr3 = xr[3];
            const float4* ar = (const float4*)(edge_attr + (size_t)mt.z * D_EDGE) + qq * 4;
            af0 = ar[0]; af1 = ar[1]; af2 = ar[2]; af3 = ar[3];
        }
        sc = (tid < 64 && tile * 64 + tid < E) ? meta[tile * 64 + tid].y : -1;
    }

    for (; tile < ntiles; tile += stride_t) {
        if (vld) {
            *(uint4*)&h[e][qq * 32 +  0] = xr0;
            *(uint4*)&h[e][qq * 32 +  8] = xr1;
            *(uint4*)&h[e][qq * 32 + 16] = xr2;
            *(uint4*)&h[e][qq * 32 + 24] = xr3;
            uint4 o;
            o.x = cvtpk(af0.x, af0.y); o.y = cvtpk(af0.z, af0.w);
            o.z = cvtpk(af1.x, af1.y); o.w = cvtpk(af1.z, af1.w);
            *(uint4*)&h[e][128 + qq * 16] = o;
            o.x = cvtpk(af2.x, af2.y); o.y = cvtpk(af2.z, af2.w);
            o.z = cvtpk(af3.x, af3.y); o.w = cvtpk(af3.z, af3.w);
            *(uint4*)&h[e][128 + qq * 16 + 8] = o;
        } else {
            uint4 z = make_uint4(0u, 0u, 0u, 0u);
            *(uint4*)&h[e][qq * 32 +  0] = z;
            *(uint4*)&h[e][qq * 32 +  8] = z;
            *(uint4*)&h[e][qq * 32 + 16] = z;
            *(uint4*)&h[e][qq * 32 + 24] = z;
            *(uint4*)&h[e][128 + qq * 16]     = z;
            *(uint4*)&h[e][128 + qq * 16 + 8] = z;
        }
        if (tid < 64) scol2[pp][tid] = sc;
        __syncthreads();                       // B1: h + scol ready

        {
            const int nt = tile + stride_t;
            const int ge = nt * 64 + e;
            vld = (nt < ntiles) && (ge < E);
            if (vld) {
                const int4 mt = meta[ge];
                const uint4* xr = (const uint4*)(xb + (size_t)mt.x * D_NODE) + qq * 4;
                xr0 = xr[0]; xr1 = xr[1]; xr2 = xr[2]; xr3 = xr[3];
                const float4* ar = (const float4*)(edge_attr + (size_t)mt.z * D_EDGE) + qq * 4;
                af0 = ar[0]; af1 = ar[1]; af2 = ar[2]; af3 = ar[3];
            }
            sc = (nt < ntiles && tid < 64 && nt * 64 + tid < E)
                   ? meta[nt * 64 + tid].y : -1;
        }

        f32x4 acc[4][2];
        #pragma unroll
        for (int et = 0; et < 4; ++et)
            #pragma unroll
            for (int c2 = 0; c2 < 2; ++c2)
                acc[et][c2] = (f32x4){0.f, 0.f, 0.f, 0.f};

        #pragma unroll
        for (int et = 0; et < 4; ++et) {
            bf16x8 Afr[6];
            #pragma unroll
            for (int kt = 0; kt < 6; ++kt)
                Afr[kt] = *(const bf16x8*)&h[et * 16 + lm][kt * 32 + q8];
            #pragma unroll
            for (int c2 = 0; c2 < 2; ++c2)
                #pragma unroll
                for (int kt = 0; kt < 6; ++kt)
                    acc[et][c2] = __builtin_amdgcn_mfma_f32_16x16x32_bf16(
                        Afr[kt], Bfr[c2][kt], acc[et][c2], 0, 0, 0);
        }

        #pragma unroll
        for (int et = 0; et < 4; ++et) {
            #pragma unroll
            for (int r = 0; r < 4; ++r) {
                float v0 = acc[et][0][r] + b1v[0];
                float v1 = acc[et][1][r] + b1v[1];
                acc[et][0][r] = v0;
                acc[et][1][r] = v1;
                float s  = red16(v0 + v1);
                float s2 = red16(v0 * v0 + v1 * v1);
                if (lm == 0) {
                    const int em = et * 16 + q * 4 + r;
                    rS [em][w] = s;
                    rS2[em][w] = s2;
                }
            }
        }
        __syncthreads();                       // B2: rS ready; ALL h reads done

        #pragma unroll
        for (int et = 0; et < 4; ++et) {
            float yv[2][4];
            #pragma unroll
            for (int r = 0; r < 4; ++r) {
                const int em = et * 16 + q * 4 + r;
                float4 p  = *(const float4*)&rS [em][0];
                float4 p2 = *(const float4*)&rS2[em][0];
                const float S    = (p.x  + p.y)  + (p.z  + p.w);
                const float S2   = (p2.x + p2.y) + (p2.z + p2.w);
                const float mu   = S * (1.f / 128.f);
                const float var  = S2 * (1.f / 128.f) - mu * mu;
                const float rstd = rsqrtf(var + LN_EPS);
                #pragma unroll
                for (int c2 = 0; c2 < 2; ++c2) {
                    float y = (acc[et][c2][r] - mu) * rstd * g1v[c2] + bev[c2];
                    y = (y > 0.f) ? y : NEG * y;
                    yv[c2][r] = y;
                }
            }
            #pragma unroll
            for (int c2 = 0; c2 < 2; ++c2) {
                const int cl = c2 * 16 + lm;            // col-local 0..31
                const int ch = ((et * 2 + (q >> 1)) ^ (lm & 7)) & 7;
                uint2 o;
                o.x = cvtpk(yv[c2][0], yv[c2][1]);
                o.y = cvtpk(yv[c2][2], yv[c2][3]);
                *(uint2*)&yT[cl][ch * 8 + (q & 1) * 4] = o;
            }
        }

        {
            bf16x8 afr[2][2];
            #pragma unroll
            for (int ct = 0; ct < 2; ++ct)
                #pragma unroll
                for (int kt = 0; kt < 2; ++kt) {
                    const int cl = ct * 16 + lm;
                    const int ch = ((kt * 4 + q) ^ (lm & 7)) & 7;
                    afr[ct][kt] = *(const bf16x8*)&yT[cl][ch * 8];
                }

            int me = scol2[pp][l];
            int pv = __shfl_up(me, 1);
            if (l == 0) pv = me ^ 1;                    // force run start at 0
            const unsigned long long m = __ballot(me != pv);
            const int nr = (int)__popcll(m);
            const int rl = (int)__popcll(m & ((2ull << l) - 1)) - 1;
            if (me != pv) rdest[rl] = me;               // redundant across waves

            for (int rt = 0; rt * 16 < nr; ++rt) {
                const int rr = rt * 16 + lm;
                bf16x8 bb[2];
                #pragma unroll
                for (int kt = 0; kt < 2; ++kt) {
                    const int eb0 = kt * 32 + q8;
                    int rid = (int)__popcll(m & ((2ull << eb0) - 1)) - 1;
                    unsigned pk[4];
                    #pragma unroll
                    for (int jp = 0; jp < 4; ++jp) {
                        unsigned lo = (rid == rr) ? 0x3F80u : 0u;
                        rid += (int)((m >> (eb0 + 2 * jp + 1)) & 1ull);
                        unsigned hi = (rid == rr) ? 0x3F80u : 0u;
                        if (jp < 3) rid += (int)((m >> (eb0 + 2 * jp + 2)) & 1ull);
                        pk[jp] = lo | (hi << 16);
                    }
                    uint4 pku = make_uint4(pk[0], pk[1], pk[2], pk[3]);
                    bb[kt] = __builtin_bit_cast(bf16x8, pku);
                }
                f32x4 o0 = (f32x4){0.f, 0.f, 0.f, 0.f};
                f32x4 o1 = (f32x4){0.f, 0.f, 0.f, 0.f};
                #pragma unroll
                for (int kt = 0; kt < 2; ++kt) {
                    o0 = __builtin_amdgcn_mfma_f32_16x16x32_bf16(
                        afr[0][kt], bb[kt], o0, 0, 0, 0);
                    o1 = __builtin_amdgcn_mfma_f32_16x16x32_bf16(
                        afr[1][kt], bb[kt], o1, 0, 0, 0);
                }
                if (rr < nr) {
                    const int dest = rdest[rr];
                    if (dest >= 0) {
                        const bool at = (rr == 0) || (rr == nr - 1);
                        float* p0 = &sums[(size_t)dest * D_NODE + w * 32 + q * 4];
                        if (at) {
                            #pragma unroll
                            for (int r = 0; r < 4; ++r) {
                                atomicAdd(&p0[r],      o0[r]);
                                atomicAdd(&p0[16 + r], o1[r]);
                            }
                        } else {
                            *(f32x4*)p0        = o0;
                            *(f32x4*)(p0 + 16) = o1;
                        }
                    }
                }
            }
        }
        pp ^= 1;
    }
}

// ---------------------------------------------------------------------------
// Node kernel (UNCHANGED from round 6).
// ---------------------------------------------------------------------------
__global__ __launch_bounds__(256) void node_mfma(
    const float* __restrict__ sums,
    const int*   __restrict__ hist,
    const float* __restrict__ x,
    const float* __restrict__ W2,
    const float* __restrict__ b2,
    const float* __restrict__ g2,
    const float* __restrict__ be2,
    float* __restrict__ out,
    int N)
{
    __shared__ __align__(16) unsigned short h[64][136];     // 17.4 KB
    __shared__ float rS [64][4], rS2[64][4];

    const int tid = threadIdx.x;
    const int w   = tid >> 6;
    const int l   = tid & 63;
    const int lm  = l & 15;
    const int q   = l >> 4;
    const int q8  = q * 8;

    bf16x8 Bfr[2][4];
    float  b2v[2], g2v[2], bev[2];
    #pragma unroll
    for (int c2 = 0; c2 < 2; ++c2) {
        const int n = (2 * w + c2) * 16 + lm;
        b2v[c2] = b2[n]; g2v[c2] = g2[n]; bev[c2] = be2[n];
        #pragma unroll
        for (int kt = 0; kt < 4; ++kt) {
            bf16x8 f;
            #pragma unroll
            for (int j = 0; j < 8; ++j)
                f[j] = (short)f2bf(W2[(kt * 32 + q8 + j) * 128 + n]);
            Bfr[c2][kt] = f;
        }
    }

    const int n0 = blockIdx.x * 64;

    {
        const int e  = tid >> 2;
        const int qq = tid & 3;
        const int gn = n0 + e;
        if (gn < N) {
            const int cnt = hist[gn];
            const float sc = (cnt > 0) ? 1.f / (float)cnt : 0.f;
            const float4* sr = (const float4*)(sums + (size_t)gn * D_NODE);
            #pragma unroll
            for (int i = 0; i < 8; ++i) {
                float4 v = sr[qq * 8 + i];
                *(uint2*)&h[e][qq * 32 + i * 4] =
                    make_uint2(cvtpk(v.x * sc, v.y * sc), cvtpk(v.z * sc, v.w * sc));
            }
        } else {
            #pragma unroll
            for (int i = 0; i < 8; ++i)
                *(uint2*)&h[e][qq * 32 + i * 4] = make_uint2(0u, 0u);
        }
    }
    __syncthreads();

    f32x4 acc[4][2];
    #pragma unroll
    for (int et = 0; et < 4; ++et)
        #pragma unroll
        for (int c2 = 0; c2 < 2; ++c2)
            acc[et][c2] = (f32x4){0.f, 0.f, 0.f, 0.f};

    #pragma unroll
    for (int et = 0; et < 4; ++et) {
        bf16x8 Afr[4];
        #pragma unroll
        for (int kt = 0; kt < 4; ++kt)
            Afr[kt] = *(const bf16x8*)&h[et * 16 + lm][kt * 32 + q8];
        #pragma unroll
        for (int c2 = 0; c2 < 2; ++c2)
            #pragma unroll
            for (int kt = 0; kt < 4; ++kt)
                acc[et][c2] = __builtin_amdgcn_mfma_f32_16x16x32_bf16(
                    Afr[kt], Bfr[c2][kt], acc[et][c2], 0, 0, 0);
    }

    #pragma unroll
    for (int et = 0; et < 4; ++et) {
        #pragma unroll
        for (int r = 0; r < 4; ++r) {
            float v0 = acc[et][0][r] + b2v[0];
            float v1 = acc[et][1][r] + b2v[1];
            acc[et][0][r] = v0;
            acc[et][1][r] = v1;
            float s  = red16(v0 + v1);
            float s2 = red16(v0 * v0 + v1 * v1);
            if (lm == 0) {
                const int em = et * 16 + q * 4 + r;
                rS [em][w] = s;
                rS2[em][w] = s2;
            }
        }
    }
    __syncthreads();

    #pragma unroll
    for (int et = 0; et < 4; ++et) {
        #pragma unroll
        for (int r = 0; r < 4; ++r) {
            const int em = et * 16 + q * 4 + r;
            const int gn = n0 + em;
            if (gn >= N) continue;
            float4 p  = *(const float4*)&rS [em][0];
            float4 p2 = *(const float4*)&rS2[em][0];
            const float S    = (p.x  + p.y)  + (p.z  + p.w);
            const float S2   = (p2.x + p2.y) + (p2.z + p2.w);
            const float mu   = S * (1.f / 128.f);
            const float var  = S2 * (1.f / 128.f) - mu * mu;
            const float rstd = rsqrtf(var + LN_EPS);
            #pragma unroll
            for (int c2 = 0; c2 < 2; ++c2) {
                const int col = (2 * w + c2) * 16 + lm;
                float y = (acc[et][c2][r] - mu) * rstd * g2v[c2] + bev[c2];
                y = (y > 0.f) ? y : NEG * y;
                float rr = y + x[(size_t)gn * D_NODE + col];
                rr = (rr > 0.f) ? rr : NEG * rr;
                out[(size_t)gn * D_NODE + col] = rr;
            }
        }
    }
}

// ---------------------------------------------------------------------------
extern "C" void kernel_launch(void* const* d_in, const int* in_sizes, int n_in,
                              void* d_out, int out_size, void* d_ws, size_t ws_size,
                              hipStream_t stream) {
    const float* x          = (const float*)d_in[0];
    const int*   edge_index = (const int*)  d_in[1];
    const float* edge_attr  = (const float*)d_in[2];
    const float* W1         = (const float*)d_in[3];
    const float* b1         = (const float*)d_in[4];
    const float* g1         = (const float*)d_in[5];
    const float* be1        = (const float*)d_in[6];
    const float* W2         = (const float*)d_in[7];
    const float* b2         = (const float*)d_in[8];
    const float* g2         = (const float*)d_in[9];
    const float* be2        = (const float*)d_in[10];

    const int N = in_sizes[0] / D_NODE;     // 50000
    const int E = in_sizes[1] / 2;          // 600000

    float* sums     = (float*)d_ws;                        // N*128 f32
    int*   hist     = (int*)(sums + (size_t)N * D_NODE);   // N
    int*   base     = hist + N;                            // N
    int*   blockTot = base + N;                            // 64
    int4*  meta     = (int4*)(blockTot + 64);              // E int4 (16B aligned)
    unsigned short* xb = (unsigned short*)(meta + E);      // N*128 bf16

    // zero sums + hist in one shot
    hipMemsetAsync(d_ws, 0, ((size_t)N * D_NODE + (size_t)N) * sizeof(float), stream);

    const int n8 = N * (D_NODE / 8);
    // launch 1: pack x + histogram (merged)
    k_pre<<<dim3(1024), dim3(256), 0, stream>>>(x, xb, n8, edge_index, hist, E);

    const int NB = (N + 1023) / 1024;                      // 49 (<=64)
    // launch 2: per-block exclusive scan
    k_scanA<<<dim3(NB), dim3(1024), 0, stream>>>(hist, base, blockTot, N);
    // launch 3: block-offset scan folded into the add pass
    k_scanC<<<dim3(NB), dim3(1024), 0, stream>>>(base, blockTot, N, NB);
    // launch 4: bucket (2x TLP vs before)
    k_bucket<<<dim3(512), dim3(256), 0, stream>>>(edge_index, base, meta, E);

    const int ntiles = (E + 63) / 64;
    const int grid   = ntiles < 1024 ? ntiles : 1024;      // 4 blocks/CU
    // launch 5
    edge_mfma_seg<<<dim3(grid), dim3(256), 0, stream>>>(
        xb, edge_attr, meta, W1, b1, g1, be1, sums, E, ntiles);

    // launch 6
    node_mfma<<<dim3((N + 63) / 64), dim3(256), 0, stream>>>(
        sums, hist, x, W2, b2, g2, be2, (float*)d_out, N);
}

// Round 8
// 434.112 us; speedup vs baseline: 1.0178x; 1.0178x over previous
//
#include <hip/hip_runtime.h>

#define D_NODE 128
#define D_EDGE 64
#define D_IN   192
#define NEG    0.01f
#define LN_EPS 1e-5f

typedef short bf16x8 __attribute__((ext_vector_type(8)));
typedef float f32x4  __attribute__((ext_vector_type(4)));

__device__ __forceinline__ unsigned f2bf(float f) {
    unsigned u = __builtin_bit_cast(unsigned, f);
    return (u + 0x7FFFu + ((u >> 16) & 1u)) >> 16;   // RNE
}
__device__ __forceinline__ unsigned pk2(float a, float b) {
    return f2bf(a) | (f2bf(b) << 16);
}
__device__ __forceinline__ float bf2f(unsigned short s) {
    unsigned u = ((unsigned)s) << 16;
    return __builtin_bit_cast(float, u);
}
// HW packed f32->bf16 (RNE), 1 instr for 2 values (no builtin on gfx950)
__device__ __forceinline__ unsigned cvtpk(float a, float b) {
    unsigned r;
    asm("v_cvt_pk_bf16_f32 %0, %1, %2" : "=v"(r) : "v"(a), "v"(b));
    return r;
}
// 16-lane sum via DPP (pure VALU, no LDS routing)
template <int C>
__device__ __forceinline__ float dppadd(float v) {
    int y = __builtin_amdgcn_update_dpp(0, __builtin_bit_cast(int, v),
                                        C, 0xF, 0xF, true);
    return v + __builtin_bit_cast(float, y);
}
__device__ __forceinline__ float red16(float v) {
    v = dppadd<0xB1>(v);
    v = dppadd<0x4E>(v);
    v = dppadd<0x141>(v);
    v = dppadd<0x140>(v);
    return v;
}

// ---------------------------------------------------------------------------
// Merged first stage: pack x -> bf16, histogram edge destinations, AND
// transpose-pack W1/W2 -> bf16 col-major (W1tb[n][k], W2tb[n][k]) so the
// MFMA kernels load B-fragments as single uint4s (kills 782x-redundant
// scalar W2 loads + f2bf chains in node_mfma).
// ---------------------------------------------------------------------------
__global__ void k_pre(const float* __restrict__ x, unsigned short* __restrict__ xb,
                      int n8, const int* __restrict__ ei, int* __restrict__ hist,
                      int E,
                      const float* __restrict__ W1, unsigned short* __restrict__ W1tb,
                      const float* __restrict__ W2, unsigned short* __restrict__ W2tb) {
    int i = blockIdx.x * blockDim.x + threadIdx.x;
    int stride = gridDim.x * blockDim.x;
    for (int t = i; t < n8; t += stride) {
        const float4* p = (const float4*)x + (size_t)t * 2;
        float4 a = p[0], b = p[1];
        uint4 o;
        o.x = pk2(a.x, a.y); o.y = pk2(a.z, a.w);
        o.z = pk2(b.x, b.y); o.w = pk2(b.z, b.w);
        ((uint4*)xb)[t] = o;
    }
    // W1tb[n][k] = bf16(W1[k][n]), n<128, k<192  (3072 uint4 stores)
    for (int t = i; t < 128 * 24; t += stride) {
        const int n  = t / 24;
        const int k8 = (t % 24) * 8;
        uint4 o;
        o.x = pk2(W1[(k8 + 0) * 128 + n], W1[(k8 + 1) * 128 + n]);
        o.y = pk2(W1[(k8 + 2) * 128 + n], W1[(k8 + 3) * 128 + n]);
        o.z = pk2(W1[(k8 + 4) * 128 + n], W1[(k8 + 5) * 128 + n]);
        o.w = pk2(W1[(k8 + 6) * 128 + n], W1[(k8 + 7) * 128 + n]);
        *(uint4*)&W1tb[n * 192 + k8] = o;
    }
    // W2tb[n][k] = bf16(W2[k][n]), n<128, k<128  (2048 uint4 stores)
    for (int t = i; t < 128 * 16; t += stride) {
        const int n  = t / 16;
        const int k8 = (t % 16) * 8;
        uint4 o;
        o.x = pk2(W2[(k8 + 0) * 128 + n], W2[(k8 + 1) * 128 + n]);
        o.y = pk2(W2[(k8 + 2) * 128 + n], W2[(k8 + 3) * 128 + n]);
        o.z = pk2(W2[(k8 + 4) * 128 + n], W2[(k8 + 5) * 128 + n]);
        o.w = pk2(W2[(k8 + 6) * 128 + n], W2[(k8 + 7) * 128 + n]);
        *(uint4*)&W2tb[n * 128 + k8] = o;
    }
    for (int e = i; e < E; e += stride) atomicAdd(&hist[ei[E + e]], 1);
}

__global__ __launch_bounds__(1024) void k_scanA(const int* __restrict__ hist,
                                                int* __restrict__ base,
                                                int* __restrict__ blockTot, int N) {
    __shared__ int wsum[16], woff[16];
    const int t = threadIdx.x, b = blockIdx.x;
    const int i = b * 1024 + t;
    const int lane = t & 63, w = t >> 6;
    int v = (i < N) ? hist[i] : 0;
    int x = v;
    #pragma unroll
    for (int d = 1; d < 64; d <<= 1) { int u = __shfl_up(x, d); if (lane >= d) x += u; }
    if (lane == 63) wsum[w] = x;
    __syncthreads();
    if (t < 16) {
        int y = wsum[t];
        #pragma unroll
        for (int d = 1; d < 16; d <<= 1) { int u = __shfl_up(y, d, 16); if (t >= d) y += u; }
        woff[t] = y - wsum[t];
    }
    __syncthreads();
    int incl = x + woff[w];
    if (i < N) base[i] = incl - v;            // exclusive within block
    if (t == 1023) blockTot[b] = incl;
}

// scanC with scanB folded in (round 7).
__global__ __launch_bounds__(1024) void k_scanC(int* __restrict__ base,
                                                const int* __restrict__ blockTot,
                                                int N, int NB) {
    __shared__ int off_sh;
    const int t = threadIdx.x;
    if (t < 64) {
        int v = (t < NB) ? blockTot[t] : 0;
        int x = v;
        #pragma unroll
        for (int d = 1; d < 64; d <<= 1) { int u = __shfl_up(x, d); if (t >= d) x += u; }
        if (t == blockIdx.x) off_sh = x - v;
    }
    __syncthreads();
    int i = blockIdx.x * 1024 + t;
    if (i < N) base[i] += off_sh;
}

// meta[p] = (srcrow | dstcol<<16, eid): ONE 8B scattered store per edge.
// N = 50000 < 2^16 so both ids fit 16 bits.
__global__ void k_bucket(const int* __restrict__ ei, int* __restrict__ base,
                         int2* __restrict__ meta, int E) {
    int i = blockIdx.x * blockDim.x + threadIdx.x;
    int stride = gridDim.x * blockDim.x;
    for (int e = i; e < E; e += stride) {
        int c = ei[E + e];
        int r = ei[e];
        int p = atomicAdd(&base[c], 1);       // consumes base (cursor)
        meta[p] = make_int2(r | (c << 16), e);
    }
}

// ---------------------------------------------------------------------------
// Edge kernel (round-6 structure; only Bfr init (W1tb uint4) and int2 meta
// changed — math identical):
// 2-barrier pipeline + register prefetch; post-B2 wave-local seg-reduce via
// MFMA with in-register P^T; DPP LN reduce; cvt_pk packing.
// ---------------------------------------------------------------------------
__global__ __launch_bounds__(256) void edge_mfma_seg(
    const unsigned short* __restrict__ xb,
    const float* __restrict__ edge_attr,
    const int2*  __restrict__ meta,
    const unsigned short* __restrict__ W1tb,
    const float* __restrict__ b1,
    const float* __restrict__ g1,
    const float* __restrict__ be1,
    float* __restrict__ sums,
    int E, int ntiles)
{
    __shared__ __align__(16) unsigned short h[64][200];   // 25.6 KB
    __shared__ float rS [64][4], rS2[64][4];
    __shared__ int   scol2[2][64];
    __shared__ int   rdest[64];

    const int tid = threadIdx.x;
    const int w   = tid >> 6;
    const int l   = tid & 63;
    const int lm  = l & 15;
    const int q   = l >> 4;
    const int q8  = q * 8;
    const int e   = tid >> 2;                 // = 16w + (l>>2): wave-aligned rows
    const int qq  = tid & 3;

    unsigned short (*yT)[64] = (unsigned short (*)[64])(&h[w * 16][0]);

    bf16x8 Bfr[2][6];
    float  b1v[2], g1v[2], bev[2];
    #pragma unroll
    for (int c2 = 0; c2 < 2; ++c2) {
        const int n = (2 * w + c2) * 16 + lm;
        b1v[c2] = b1[n]; g1v[c2] = g1[n]; bev[c2] = be1[n];
        #pragma unroll
        for (int kt = 0; kt < 6; ++kt)
            Bfr[c2][kt] = *(const bf16x8*)&W1tb[n * 192 + kt * 32 + q8];
    }

    const int stride_t = gridDim.x;
    int tile = blockIdx.x;
    int pp   = 0;

    uint4  xr0, xr1, xr2, xr3;
    float4 af0, af1, af2, af3;
    int    sc;
    bool   vld;
    {
        const int ge = tile * 64 + e;
        vld = (ge < E);
        if (vld) {
            const int2 mt = meta[ge];
            const int row = mt.x & 0xFFFF;
            const uint4* xr = (const uint4*)(xb + (size_t)row * D_NODE) + qq * 4;
            xr0 = xr[0]; xr1 = xr[1]; xr2 = xr[2]; xr3 = xr[3];
            const float4* ar = (const float4*)(edge_attr + (size_t)mt.y * D_EDGE) + qq * 4;
            af0 = ar[0]; af1 = ar[1]; af2 = ar[2]; af3 = ar[3];
        }
        sc = (tid < 64 && tile * 64 + tid < E)
               ? (int)((unsigned)meta[tile * 64 + tid].x >> 16) : -1;
    }

    for (; tile < ntiles; tile += stride_t) {
        if (vld) {
            *(uint4*)&h[e][qq * 32 +  0] = xr0;
            *(uint4*)&h[e][qq * 32 +  8] = xr1;
            *(uint4*)&h[e][qq * 32 + 16] = xr2;
            *(uint4*)&h[e][qq * 32 + 24] = xr3;
            uint4 o;
            o.x = cvtpk(af0.x, af0.y); o.y = cvtpk(af0.z, af0.w);
            o.z = cvtpk(af1.x, af1.y); o.w = cvtpk(af1.z, af1.w);
            *(uint4*)&h[e][128 + qq * 16] = o;
            o.x = cvtpk(af2.x, af2.y); o.y = cvtpk(af2.z, af2.w);
            o.z = cvtpk(af3.x, af3.y); o.w = cvtpk(af3.z, af3.w);
            *(uint4*)&h[e][128 + qq * 16 + 8] = o;
        } else {
            uint4 z = make_uint4(0u, 0u, 0u, 0u);
            *(uint4*)&h[e][qq * 32 +  0] = z;
            *(uint4*)&h[e][qq * 32 +  8] = z;
            *(uint4*)&h[e][qq * 32 + 16] = z;
            *(uint4*)&h[e][qq * 32 + 24] = z;
            *(uint4*)&h[e][128 + qq * 16]     = z;
            *(uint4*)&h[e][128 + qq * 16 + 8] = z;
        }
        if (tid < 64) scol2[pp][tid] = sc;
        __syncthreads();                       // B1: h + scol ready

        {
            const int nt = tile + stride_t;
            const int ge = nt * 64 + e;
            vld = (nt < ntiles) && (ge < E);
            if (vld) {
                const int2 mt = meta[ge];
                const int row = mt.x & 0xFFFF;
                const uint4* xr = (const uint4*)(xb + (size_t)row * D_NODE) + qq * 4;
                xr0 = xr[0]; xr1 = xr[1]; xr2 = xr[2]; xr3 = xr[3];
                const float4* ar = (const float4*)(edge_attr + (size_t)mt.y * D_EDGE) + qq * 4;
                af0 = ar[0]; af1 = ar[1]; af2 = ar[2]; af3 = ar[3];
            }
            sc = (nt < ntiles && tid < 64 && nt * 64 + tid < E)
                   ? (int)((unsigned)meta[nt * 64 + tid].x >> 16) : -1;
        }

        f32x4 acc[4][2];
        #pragma unroll
        for (int et = 0; et < 4; ++et)
            #pragma unroll
            for (int c2 = 0; c2 < 2; ++c2)
                acc[et][c2] = (f32x4){0.f, 0.f, 0.f, 0.f};

        #pragma unroll
        for (int et = 0; et < 4; ++et) {
            bf16x8 Afr[6];
            #pragma unroll
            for (int kt = 0; kt < 6; ++kt)
                Afr[kt] = *(const bf16x8*)&h[et * 16 + lm][kt * 32 + q8];
            #pragma unroll
            for (int c2 = 0; c2 < 2; ++c2)
                #pragma unroll
                for (int kt = 0; kt < 6; ++kt)
                    acc[et][c2] = __builtin_amdgcn_mfma_f32_16x16x32_bf16(
                        Afr[kt], Bfr[c2][kt], acc[et][c2], 0, 0, 0);
        }

        #pragma unroll
        for (int et = 0; et < 4; ++et) {
            #pragma unroll
            for (int r = 0; r < 4; ++r) {
                float v0 = acc[et][0][r] + b1v[0];
                float v1 = acc[et][1][r] + b1v[1];
                acc[et][0][r] = v0;
                acc[et][1][r] = v1;
                float s  = red16(v0 + v1);
                float s2 = red16(v0 * v0 + v1 * v1);
                if (lm == 0) {
                    const int em = et * 16 + q * 4 + r;
                    rS [em][w] = s;
                    rS2[em][w] = s2;
                }
            }
        }
        __syncthreads();                       // B2: rS ready; ALL h reads done

        #pragma unroll
        for (int et = 0; et < 4; ++et) {
            float yv[2][4];
            #pragma unroll
            for (int r = 0; r < 4; ++r) {
                const int em = et * 16 + q * 4 + r;
                float4 p  = *(const float4*)&rS [em][0];
                float4 p2 = *(const float4*)&rS2[em][0];
                const float S    = (p.x  + p.y)  + (p.z  + p.w);
                const float S2   = (p2.x + p2.y) + (p2.z + p2.w);
                const float mu   = S * (1.f / 128.f);
                const float var  = S2 * (1.f / 128.f) - mu * mu;
                const float rstd = rsqrtf(var + LN_EPS);
                #pragma unroll
                for (int c2 = 0; c2 < 2; ++c2) {
                    float y = (acc[et][c2][r] - mu) * rstd * g1v[c2] + bev[c2];
                    y = (y > 0.f) ? y : NEG * y;
                    yv[c2][r] = y;
                }
            }
            #pragma unroll
            for (int c2 = 0; c2 < 2; ++c2) {
                const int cl = c2 * 16 + lm;            // col-local 0..31
                const int ch = ((et * 2 + (q >> 1)) ^ (lm & 7)) & 7;
                uint2 o;
                o.x = cvtpk(yv[c2][0], yv[c2][1]);
                o.y = cvtpk(yv[c2][2], yv[c2][3]);
                *(uint2*)&yT[cl][ch * 8 + (q & 1) * 4] = o;
            }
        }

        {
            bf16x8 afr[2][2];
            #pragma unroll
            for (int ct = 0; ct < 2; ++ct)
                #pragma unroll
                for (int kt = 0; kt < 2; ++kt) {
                    const int cl = ct * 16 + lm;
                    const int ch = ((kt * 4 + q) ^ (lm & 7)) & 7;
                    afr[ct][kt] = *(const bf16x8*)&yT[cl][ch * 8];
                }

            int me = scol2[pp][l];
            int pv = __shfl_up(me, 1);
            if (l == 0) pv = me ^ 1;                    // force run start at 0
            const unsigned long long m = __ballot(me != pv);
            const int nr = (int)__popcll(m);
            const int rl = (int)__popcll(m & ((2ull << l) - 1)) - 1;
            if (me != pv) rdest[rl] = me;               // redundant across waves

            for (int rt = 0; rt * 16 < nr; ++rt) {
                const int rr = rt * 16 + lm;
                bf16x8 bb[2];
                #pragma unroll
                for (int kt = 0; kt < 2; ++kt) {
                    const int eb0 = kt * 32 + q8;
                    int rid = (int)__popcll(m & ((2ull << eb0) - 1)) - 1;
                    unsigned pk[4];
                    #pragma unroll
                    for (int jp = 0; jp < 4; ++jp) {
                        unsigned lo = (rid == rr) ? 0x3F80u : 0u;
                        rid += (int)((m >> (eb0 + 2 * jp + 1)) & 1ull);
                        unsigned hi = (rid == rr) ? 0x3F80u : 0u;
                        if (jp < 3) rid += (int)((m >> (eb0 + 2 * jp + 2)) & 1ull);
                        pk[jp] = lo | (hi << 16);
                    }
                    uint4 pku = make_uint4(pk[0], pk[1], pk[2], pk[3]);
                    bb[kt] = __builtin_bit_cast(bf16x8, pku);
                }
                f32x4 o0 = (f32x4){0.f, 0.f, 0.f, 0.f};
                f32x4 o1 = (f32x4){0.f, 0.f, 0.f, 0.f};
                #pragma unroll
                for (int kt = 0; kt < 2; ++kt) {
                    o0 = __builtin_amdgcn_mfma_f32_16x16x32_bf16(
                        afr[0][kt], bb[kt], o0, 0, 0, 0);
                    o1 = __builtin_amdgcn_mfma_f32_16x16x32_bf16(
                        afr[1][kt], bb[kt], o1, 0, 0, 0);
                }
                if (rr < nr) {
                    const int dest = rdest[rr];
                    if (dest >= 0) {
                        const bool at = (rr == 0) || (rr == nr - 1);
                        float* p0 = &sums[(size_t)dest * D_NODE + w * 32 + q * 4];
                        if (at) {
                            #pragma unroll
                            for (int r = 0; r < 4; ++r) {
                                atomicAdd(&p0[r],      o0[r]);
                                atomicAdd(&p0[16 + r], o1[r]);
                            }
                        } else {
                            *(f32x4*)p0        = o0;
                            *(f32x4*)(p0 + 16) = o1;
                        }
                    }
                }
            }
        }
        pp ^= 1;
    }
}

// ---------------------------------------------------------------------------
// Node kernel: B-frags from pre-transposed W2tb (8 uint4 loads, was 64 scalar
// + 384 f2bf); x residual staged from xb into padded LDS (coalesced) instead
// of 32 scalar global loads per thread.
// ---------------------------------------------------------------------------
__global__ __launch_bounds__(256) void node_mfma(
    const float* __restrict__ sums,
    const int*   __restrict__ hist,
    const unsigned short* __restrict__ xb,
    const unsigned short* __restrict__ W2tb,
    const float* __restrict__ b2,
    const float* __restrict__ g2,
    const float* __restrict__ be2,
    float* __restrict__ out,
    int N)
{
    __shared__ __align__(16) unsigned short h[64][136];     // 17.4 KB
    __shared__ __align__(8)  unsigned short xr[64][132];    // 16.9 KB (pad: no conflicts)
    __shared__ float rS [64][4], rS2[64][4];

    const int tid = threadIdx.x;
    const int w   = tid >> 6;
    const int l   = tid & 63;
    const int lm  = l & 15;
    const int q   = l >> 4;
    const int q8  = q * 8;

    bf16x8 Bfr[2][4];
    float  b2v[2], g2v[2], bev[2];
    #pragma unroll
    for (int c2 = 0; c2 < 2; ++c2) {
        const int n = (2 * w + c2) * 16 + lm;
        b2v[c2] = b2[n]; g2v[c2] = g2[n]; bev[c2] = be2[n];
        #pragma unroll
        for (int kt = 0; kt < 4; ++kt)
            Bfr[c2][kt] = *(const bf16x8*)&W2tb[n * 128 + kt * 32 + q8];
    }

    const int n0 = blockIdx.x * 64;

    // stage m = sums/cnt (bf16) + x residual row (bf16, coalesced)
    {
        const int e  = tid >> 2;
        const int qq = tid & 3;
        const int gn = n0 + e;
        if (gn < N) {
            const int cnt = hist[gn];
            const float sc = (cnt > 0) ? 1.f / (float)cnt : 0.f;
            const float4* sr = (const float4*)(sums + (size_t)gn * D_NODE);
            #pragma unroll
            for (int i = 0; i < 8; ++i) {
                float4 v = sr[qq * 8 + i];
                *(uint2*)&h[e][qq * 32 + i * 4] =
                    make_uint2(cvtpk(v.x * sc, v.y * sc), cvtpk(v.z * sc, v.w * sc));
            }
            const uint2* xrow = (const uint2*)(xb + (size_t)gn * D_NODE) + qq * 8;
            #pragma unroll
            for (int i = 0; i < 8; ++i)
                *(uint2*)&xr[e][qq * 32 + i * 4] = xrow[i];
        } else {
            #pragma unroll
            for (int i = 0; i < 8; ++i) {
                *(uint2*)&h[e][qq * 32 + i * 4]  = make_uint2(0u, 0u);
                *(uint2*)&xr[e][qq * 32 + i * 4] = make_uint2(0u, 0u);
            }
        }
    }
    __syncthreads();

    f32x4 acc[4][2];
    #pragma unroll
    for (int et = 0; et < 4; ++et)
        #pragma unroll
        for (int c2 = 0; c2 < 2; ++c2)
            acc[et][c2] = (f32x4){0.f, 0.f, 0.f, 0.f};

    #pragma unroll
    for (int et = 0; et < 4; ++et) {
        bf16x8 Afr[4];
        #pragma unroll
        for (int kt = 0; kt < 4; ++kt)
            Afr[kt] = *(const bf16x8*)&h[et * 16 + lm][kt * 32 + q8];
        #pragma unroll
        for (int c2 = 0; c2 < 2; ++c2)
            #pragma unroll
            for (int kt = 0; kt < 4; ++kt)
                acc[et][c2] = __builtin_amdgcn_mfma_f32_16x16x32_bf16(
                    Afr[kt], Bfr[c2][kt], acc[et][c2], 0, 0, 0);
    }

    #pragma unroll
    for (int et = 0; et < 4; ++et) {
        #pragma unroll
        for (int r = 0; r < 4; ++r) {
            float v0 = acc[et][0][r] + b2v[0];
            float v1 = acc[et][1][r] + b2v[1];
            acc[et][0][r] = v0;
            acc[et][1][r] = v1;
            float s  = red16(v0 + v1);
            float s2 = red16(v0 * v0 + v1 * v1);
            if (lm == 0) {
                const int em = et * 16 + q * 4 + r;
                rS [em][w] = s;
                rS2[em][w] = s2;
            }
        }
    }
    __syncthreads();

    #pragma unroll
    for (int et = 0; et < 4; ++et) {
        #pragma unroll
        for (int r = 0; r < 4; ++r) {
            const int em = et * 16 + q * 4 + r;
            const int gn = n0 + em;
            if (gn >= N) continue;
            float4 p  = *(const float4*)&rS [em][0];
            float4 p2 = *(const float4*)&rS2[em][0];
            const float S    = (p.x  + p.y)  + (p.z  + p.w);
            const float S2   = (p2.x + p2.y) + (p2.z + p2.w);
            const float mu   = S * (1.f / 128.f);
            const float var  = S2 * (1.f / 128.f) - mu * mu;
            const float rstd = rsqrtf(var + LN_EPS);
            #pragma unroll
            for (int c2 = 0; c2 < 2; ++c2) {
                const int col = (2 * w + c2) * 16 + lm;
                float y = (acc[et][c2][r] - mu) * rstd * g2v[c2] + bev[c2];
                y = (y > 0.f) ? y : NEG * y;
                float rr = y + bf2f(xr[em][col]);
                rr = (rr > 0.f) ? rr : NEG * rr;
                out[(size_t)gn * D_NODE + col] = rr;
            }
        }
    }
}

// ---------------------------------------------------------------------------
extern "C" void kernel_launch(void* const* d_in, const int* in_sizes, int n_in,
                              void* d_out, int out_size, void* d_ws, size_t ws_size,
                              hipStream_t stream) {
    const float* x          = (const float*)d_in[0];
    const int*   edge_index = (const int*)  d_in[1];
    const float* edge_attr  = (const float*)d_in[2];
    const float* W1         = (const float*)d_in[3];
    const float* b1         = (const float*)d_in[4];
    const float* g1         = (const float*)d_in[5];
    const float* be1        = (const float*)d_in[6];
    const float* W2         = (const float*)d_in[7];
    const float* b2         = (const float*)d_in[8];
    const float* g2         = (const float*)d_in[9];
    const float* be2        = (const float*)d_in[10];

    const int N = in_sizes[0] / D_NODE;     // 50000
    const int E = in_sizes[1] / 2;          // 600000

    float* sums     = (float*)d_ws;                        // N*128 f32
    int*   hist     = (int*)(sums + (size_t)N * D_NODE);   // N
    int*   base     = hist + N;                            // N
    int*   blockTot = base + N;                            // 64
    int2*  meta     = (int2*)(blockTot + 64);              // E int2 (8B)
    unsigned short* xb   = (unsigned short*)(meta + E);    // N*128 bf16
    unsigned short* W1tb = xb + (size_t)N * D_NODE;        // 128*192 bf16
    unsigned short* W2tb = W1tb + 128 * 192;               // 128*128 bf16

    // zero sums + hist in one shot
    hipMemsetAsync(d_ws, 0, ((size_t)N * D_NODE + (size_t)N) * sizeof(float), stream);

    const int n8 = N * (D_NODE / 8);
    k_pre<<<dim3(1024), dim3(256), 0, stream>>>(x, xb, n8, edge_index, hist, E,
                                                W1, W1tb, W2, W2tb);

    const int NB = (N + 1023) / 1024;                      // 49 (<=64)
    k_scanA<<<dim3(NB), dim3(1024), 0, stream>>>(hist, base, blockTot, N);
    k_scanC<<<dim3(NB), dim3(1024), 0, stream>>>(base, blockTot, N, NB);
    k_bucket<<<dim3(512), dim3(256), 0, stream>>>(edge_index, base, meta, E);

    const int ntiles = (E + 63) / 64;
    const int grid   = ntiles < 1024 ? ntiles : 1024;      // 4 blocks/CU
    edge_mfma_seg<<<dim3(grid), dim3(256), 0, stream>>>(
        xb, edge_attr, meta, W1tb, b1, g1, be1, sums, E, ntiles);

    node_mfma<<<dim3((N + 63) / 64), dim3(256), 0, stream>>>(
        sums, hist, xb, W2tb, b2, g2, be2, (float*)d_out, N);
}